// Round 2
// baseline (43.560 us; speedup 1.0000x reference)
//
#include <hip/hip_runtime.h>

// CurvatureLoss: out = sum(|lap(pred) - lap(target)| * mask) / (sum(mask) + 1e-8)
// lap = 3x3 Laplacian [[0,1,0],[1,-4,1],[0,1,0]], zero ("SAME") padding.
// Linearity: lap(pred)-lap(target) == lap(pred-target); compute d = pred-target.
//
// R1: register-rolling 3-row window per thread (no LDS, no __syncthreads in the
// stencil loop). Horizontal neighbors via wave shuffle; wave-strip edges via two
// scalar global loads (L1/L2-hit, row was just read). ROWS=8 -> 2048 blocks ->
// 8 blocks/CU -> 32 waves/CU (full occupancy), waves fully independent.

static constexpr int IMG_W = 1024;   // fixed by reference
static constexpr int IMG_H = 1024;   // fixed by reference
static constexpr int ROWS  = 8;      // output rows per block
static constexpr int NT    = 256;    // 4 cols/thread at W=1024

__global__ __launch_bounds__(NT) void curv_partial_kernel(
    const float* __restrict__ pred,
    const float* __restrict__ target,
    const float* __restrict__ mask,
    float* __restrict__ partial,   // [2 * gridDim.x]: (loss_sum, mask_sum) per block
    int H)
{
    const int tid  = threadIdx.x;
    const int lane = tid & 63;
    const int blocksPerImage = H / ROWS;
    const int b  = blockIdx.x / blocksPerImage;
    const int y0 = (blockIdx.x % blocksPerImage) * ROWS;
    const size_t imgOff = (size_t)b * H * IMG_W;
    const int x4 = tid * 4;            // this thread's 4 columns

    auto loadD = [&](int y) -> float4 {
        if (y < 0 || y >= H) return make_float4(0.f, 0.f, 0.f, 0.f);  // zero pad
        const size_t o = imgOff + (size_t)y * IMG_W + x4;
        const float4 p = *reinterpret_cast<const float4*>(pred + o);
        const float4 t = *reinterpret_cast<const float4*>(target + o);
        return make_float4(p.x - t.x, p.y - t.y, p.z - t.z, p.w - t.w);
    };

    float4 d_prev = loadD(y0 - 1);
    float4 d_cur  = loadD(y0);

    float lsum = 0.f, msum = 0.f;

    #pragma unroll
    for (int r = 0; r < ROWS; ++r) {
        const int y = y0 + r;
        const float4 d_next = loadD(y + 1);

        // Wave-strip edge neighbors for the center row (2 lanes per wave).
        float eL = 0.f, eR = 0.f;
        if (lane == 0 && x4 != 0) {
            const size_t o = imgOff + (size_t)y * IMG_W + (x4 - 1);
            eL = pred[o] - target[o];
        }
        if (lane == 63 && x4 + 4 != IMG_W) {
            const size_t o = imgOff + (size_t)y * IMG_W + (x4 + 4);
            eR = pred[o] - target[o];
        }

        float left  = __shfl_up(d_cur.w, 1, 64);
        float right = __shfl_down(d_cur.x, 1, 64);
        if (lane == 0)  left  = eL;
        if (lane == 63) right = eR;

        const float4 m = *reinterpret_cast<const float4*>(mask + imgOff + (size_t)y * IMG_W + x4);

        const float l0 = d_prev.x + d_next.x + left    + d_cur.y - 4.f * d_cur.x;
        const float l1 = d_prev.y + d_next.y + d_cur.x + d_cur.z - 4.f * d_cur.y;
        const float l2 = d_prev.z + d_next.z + d_cur.y + d_cur.w - 4.f * d_cur.z;
        const float l3 = d_prev.w + d_next.w + d_cur.z + right   - 4.f * d_cur.w;

        lsum += fabsf(l0) * m.x + fabsf(l1) * m.y + fabsf(l2) * m.z + fabsf(l3) * m.w;
        msum += m.x + m.y + m.z + m.w;

        d_prev = d_cur;
        d_cur  = d_next;
    }

    // Wave butterfly reduce, then cross-wave via (tiny) LDS.
    for (int off = 32; off > 0; off >>= 1) {
        lsum += __shfl_down(lsum, off, 64);
        msum += __shfl_down(msum, off, 64);
    }
    __shared__ float wls[NT / 64], wms[NT / 64];
    const int wave = tid >> 6;
    if (lane == 0) { wls[wave] = lsum; wms[wave] = msum; }
    __syncthreads();
    if (tid == 0) {
        float L = 0.f, M = 0.f;
        #pragma unroll
        for (int w = 0; w < NT / 64; ++w) { L += wls[w]; M += wms[w]; }
        partial[2 * (size_t)blockIdx.x]     = L;
        partial[2 * (size_t)blockIdx.x + 1] = M;
    }
}

__global__ __launch_bounds__(256) void curv_final_kernel(
    const float* __restrict__ partial, float* __restrict__ out, int nblocks)
{
    __shared__ float sL[256], sM[256];
    float L = 0.f, M = 0.f;
    for (int i = threadIdx.x; i < nblocks; i += 256) {
        L += partial[2 * (size_t)i];
        M += partial[2 * (size_t)i + 1];
    }
    sL[threadIdx.x] = L; sM[threadIdx.x] = M;
    __syncthreads();
    for (int s = 128; s > 0; s >>= 1) {
        if (threadIdx.x < s) {
            sL[threadIdx.x] += sL[threadIdx.x + s];
            sM[threadIdx.x] += sM[threadIdx.x + s];
        }
        __syncthreads();
    }
    if (threadIdx.x == 0) out[0] = sL[0] / (sM[0] + 1e-8f);
}

extern "C" void kernel_launch(void* const* d_in, const int* in_sizes, int n_in,
                              void* d_out, int out_size, void* d_ws, size_t ws_size,
                              hipStream_t stream) {
    const float* pred   = (const float*)d_in[0];
    const float* target = (const float*)d_in[1];
    const float* mask   = (const float*)d_in[2];
    float* out = (float*)d_out;
    float* partial = (float*)d_ws;

    const int H = IMG_H;
    const int B = in_sizes[0] / (IMG_H * IMG_W);
    const int nblocks = B * (H / ROWS);   // 16 * 128 = 2048

    curv_partial_kernel<<<nblocks, NT, 0, stream>>>(pred, target, mask, partial, H);
    curv_final_kernel<<<1, 256, 0, stream>>>(partial, out, nblocks);
}